// Round 5
// baseline (1317.368 us; speedup 1.0000x reference)
//
#include <hip/hip_runtime.h>

#define N_NODES 50000
#define N_PAD   50048          // 782 * 64
#define N_EDGES 800000
#define N_REL   8
#define NSEG    (N_REL * N_NODES)      // 400000
#define SCAN_NB 391                    // ceil(NSEG / 1024)

typedef short bf16x8 __attribute__((ext_vector_type(8)));
typedef float f32x4  __attribute__((ext_vector_type(4)));

__device__ __forceinline__ ushort f2bf(float f) {
    union { float f; unsigned u; } c; c.f = f;
    unsigned u = c.u + 0x7fffu + ((c.u >> 16) & 1u);   // RNE
    return (ushort)(u >> 16);
}
__device__ __forceinline__ void add8(float* s, uint4 v) {
    unsigned u[4] = {v.x, v.y, v.z, v.w};
    #pragma unroll
    for (int k = 0; k < 4; ++k) {
        s[2 * k]     += __uint_as_float(u[k] << 16);
        s[2 * k + 1] += __uint_as_float(u[k] & 0xffff0000u);
    }
}
__device__ __forceinline__ void async16(const ushort* g, ushort* l) {
    __builtin_amdgcn_global_load_lds((const __attribute__((address_space(1))) void*)g,
                                     (__attribute__((address_space(3))) void*)l, 16, 0, 0);
}

// ---------------- edge preprocessing: counting sort by (rel*N + dst) ----------------

__global__ void count_edges(const int* __restrict__ dst, const int* __restrict__ et,
                            int* __restrict__ cnt) {
    int e = blockIdx.x * 256 + threadIdx.x;
    if (e < N_EDGES) atomicAdd(&cnt[et[e] * N_NODES + dst[e]], 1);
}

__global__ __launch_bounds__(256) void scan_pass1(const int* __restrict__ cnt,
                                                  int* __restrict__ sums) {
    __shared__ int sc[256];
    int b = blockIdx.x, t = threadIdx.x;
    int base = b * 1024 + t * 4;
    int v = 0;
    #pragma unroll
    for (int i = 0; i < 4; ++i) { int idx = base + i; if (idx < NSEG) v += cnt[idx]; }
    sc[t] = v; __syncthreads();
    for (int off = 1; off < 256; off <<= 1) {
        int x = (t >= off) ? sc[t - off] : 0;
        __syncthreads(); sc[t] += x; __syncthreads();
    }
    if (t == 255) sums[b] = sc[255];
}

__global__ __launch_bounds__(512) void scan_pass2(int* __restrict__ sums, int nb) {
    __shared__ int sc[512];
    int t = threadIdx.x;
    int v = (t < nb) ? sums[t] : 0;
    sc[t] = v; __syncthreads();
    for (int off = 1; off < 512; off <<= 1) {
        int x = (t >= off) ? sc[t - off] : 0;
        __syncthreads(); sc[t] += x; __syncthreads();
    }
    if (t < nb) sums[t] = sc[t] - v;     // exclusive
}

__global__ __launch_bounds__(256) void scan_pass3(const int* __restrict__ cnt,
                                                  const int* __restrict__ sums,
                                                  int* __restrict__ row_ptr) {
    __shared__ int sc[256];
    int b = blockIdx.x, t = threadIdx.x;
    int base = b * 1024 + t * 4;
    int e[4]; int v = 0;
    #pragma unroll
    for (int i = 0; i < 4; ++i) { int idx = base + i; e[i] = (idx < NSEG) ? cnt[idx] : 0; v += e[i]; }
    sc[t] = v; __syncthreads();
    for (int off = 1; off < 256; off <<= 1) {
        int x = (t >= off) ? sc[t - off] : 0;
        __syncthreads(); sc[t] += x; __syncthreads();
    }
    int run = sums[b] + (sc[t] - v);
    #pragma unroll
    for (int i = 0; i < 4; ++i) {
        int idx = base + i;
        if (idx < NSEG) row_ptr[idx] = run;
        run += e[i];
    }
    if (b == 0 && t == 0) row_ptr[NSEG] = N_EDGES;
}

// cnt doubles as the placement cursor (atomicSub); cnt is dead afterwards.
__global__ void place_edges(const int* __restrict__ src, const int* __restrict__ dst,
                            const int* __restrict__ et, const int* __restrict__ row_ptr,
                            int* __restrict__ cnt, int* __restrict__ sorted_src) {
    int e = blockIdx.x * 256 + threadIdx.x;
    if (e >= N_EDGES) return;
    int key = et[e] * N_NODES + dst[e];
    int old = atomicSub(&cnt[key], 1);
    sorted_src[row_ptr[key] + old - 1] = src[e];
}

// ---------------- weight pack: BT[col][kk], kk = r*K+i -> W[r][i][col], r=8 -> root ----------------

__global__ void convert_weights(const float* __restrict__ W, const float* __restrict__ root,
                                ushort* __restrict__ BT, int K, int O) {
    int KT = 9 * K;
    int idx = blockIdx.x * 256 + threadIdx.x;
    if (idx >= O * KT) return;
    int col = idx / KT, kk = idx % KT;
    int r = kk / K, i = kk % K;
    float v = (r < N_REL) ? W[((size_t)r * K + i) * O + col] : root[(size_t)i * O + col];
    BT[idx] = f2bf(v);
}

__global__ void f32_to_bf16(const float* __restrict__ in, ushort* __restrict__ out, int n4) {
    int i = blockIdx.x * 256 + threadIdx.x;
    if (i >= n4) return;
    float4 v = ((const float4*)in)[i];
    ushort4 s; s.x = f2bf(v.x); s.y = f2bf(v.y); s.z = f2bf(v.z); s.w = f2bf(v.w);
    ((ushort4*)out)[i] = s;
}

// ---------------- fused RGCN layer: gather-aggregate into LDS + MFMA GEMM ----------------
// Block = 64 dst rows x O cols. Loop r=0..8: build A-tile (mean over relation-r edges of
// h[src], r=8 = identity/root) in LDS, then BK=32 MFMA k-loop over that relation's K slice.
// h is L2/L3-resident (~25 MB) so gather reads rarely touch HBM; no Agg intermediate.
template<int K, int O, bool LAST>
__global__ __launch_bounds__(256)
void fused_layer(const ushort* __restrict__ h, const ushort* __restrict__ BT,
                 const float* __restrict__ bias,
                 const int* __restrict__ row_ptr, const int* __restrict__ sorted_src,
                 ushort* __restrict__ Cb, float* __restrict__ Cf) {
    constexpr int KT = 9 * K;
    constexpr int AP = K + 8;             // padded A row stride (ushorts), 16B-aligned
    __shared__ ushort As[64 * AP];
    __shared__ ushort Bs[O * 32];
    const int t = threadIdx.x;
    const int lane = t & 63;
    const int w = t >> 6;
    const int l16 = lane & 15, q = lane >> 4;
    const int d0 = blockIdx.x * 64;

    // wave tiling of the 64 x O output
    constexpr int NI = (O == 256) ? 4 : 2;
    constexpr int NJ = (O == 256) ? 4 : 2;
    const int wm = (O == 256) ? 0 : (w & 1) * 32;
    const int wn = (O == 256) ? w * 64 : (w >> 1) * 32;

    f32x4 acc[NI][NJ] = {};

    constexpr int TPN = K / 8;            // threads per dst row (chunks of 8 cols)
    constexpr int DPB = 256 / TPN;        // dst rows per pass
    const int td = t / TPN;
    const int c0 = (t % TPN) * 8;

    for (int r = 0; r < 9; ++r) {
        __syncthreads();                  // previous relation's MFMA reads of As done
        // ---- gather phase: A-tile for relation r ----
        #pragma unroll
        for (int p = 0; p < 64 / DPB; ++p) {
            int dd = p * DPB + td;        // 0..63
            int d  = d0 + dd;
            ushort* dstp = &As[dd * AP + c0];
            if (r == N_REL) {             // identity slice (root operand); d < N_PAD always
                *(uint4*)dstp = *(const uint4*)(h + (size_t)d * K + c0);
            } else if (d >= N_NODES) {
                *(uint4*)dstp = make_uint4(0u, 0u, 0u, 0u);
            } else {
                int base = r * N_NODES + d;
                int s0 = row_ptr[base], s1 = row_ptr[base + 1];
                float sum[8] = {};
                for (int e = s0; e < s1; ++e)
                    add8(sum, *(const uint4*)(h + (size_t)sorted_src[e] * K + c0));
                float inv = (s1 > s0) ? 1.0f / (float)(s1 - s0) : 0.0f;
                ushort o[8];
                #pragma unroll
                for (int k2 = 0; k2 < 8; ++k2) o[k2] = f2bf(sum[k2] * inv);
                *(uint4*)dstp = *(const uint4*)o;
            }
        }
        // ---- MFMA phase over this relation's K slice ----
        for (int k0 = 0; k0 < K; k0 += 32) {
            __syncthreads();              // Bs free (prev step) / As writes visible
            // stage B-tile [O cols x 32 k]: chunk ci -> col=ci>>2, koff=(ci&3)*8
            {
                int ci = w * 64 + lane;
                #pragma unroll
                for (int cb = 0; cb < O / 64; ++cb) {
                    int c = ci + cb * 256;
                    async16(BT + (size_t)(c >> 2) * KT + r * K + k0 + ((c & 3) << 3),
                            &Bs[c * 8]);
                }
            }
            __syncthreads();              // drains global_load_lds (vmcnt 0)
            bf16x8 a[NI], b[NJ];
            #pragma unroll
            for (int i = 0; i < NI; ++i)
                a[i] = *(const bf16x8*)&As[(wm + i * 16 + l16) * AP + k0 + q * 8];
            #pragma unroll
            for (int j = 0; j < NJ; ++j)
                b[j] = *(const bf16x8*)&Bs[(wn + j * 16 + l16) * 32 + q * 8];
            #pragma unroll
            for (int i = 0; i < NI; ++i)
                #pragma unroll
                for (int j = 0; j < NJ; ++j)
                    acc[i][j] = __builtin_amdgcn_mfma_f32_16x16x32_bf16(a[i], b[j], acc[i][j], 0, 0, 0);
        }
    }

    // ---- epilogue: bias + ReLU, D mapping col=l16, row=q*4+reg (verified) ----
    #pragma unroll
    for (int i = 0; i < NI; ++i) {
        int grow = d0 + wm + i * 16 + q * 4;
        #pragma unroll
        for (int j = 0; j < NJ; ++j) {
            int gcol = wn + j * 16 + l16;
            float bv = bias[gcol];
            #pragma unroll
            for (int rg = 0; rg < 4; ++rg) {
                float v = acc[i][j][rg] + bv;
                if (!LAST) {
                    v = fmaxf(v, 0.0f);
                    Cb[(size_t)(grow + rg) * O + gcol] = f2bf(v);
                } else if (grow + rg < N_NODES) {
                    Cf[(size_t)(grow + rg) * O + gcol] = v;
                }
            }
        }
    }
}

// ---------------- host side ----------------

extern "C" void kernel_launch(void* const* d_in, const int* in_sizes, int n_in,
                              void* d_out, int out_size, void* d_ws, size_t ws_size,
                              hipStream_t stream) {
    const float* x  = (const float*)d_in[0];
    const int*   ei = (const int*)d_in[1];
    const int*   et = (const int*)d_in[2];
    const float* W[4]  = {(const float*)d_in[3], (const float*)d_in[6], (const float*)d_in[9],  (const float*)d_in[12]};
    const float* RT[4] = {(const float*)d_in[4], (const float*)d_in[7], (const float*)d_in[10], (const float*)d_in[13]};
    const float* BI[4] = {(const float*)d_in[5], (const float*)d_in[8], (const float*)d_in[11], (const float*)d_in[14]};
    const int KS[4] = {128, 256, 256, 256};
    const int OS[4] = {256, 256, 256, 64};
    const int* src = ei;
    const int* dst = ei + N_EDGES;

    // ---- workspace carve-up (~65 MB) ----
    char* ws = (char*)d_ws;
    size_t off = 0;
    auto take = [&](size_t bytes) -> char* {
        char* p = ws + off;
        off = (off + bytes + 255) & ~(size_t)255;
        return p;
    };
    int* cnt        = (int*)take((size_t)NSEG * 4);
    int* row_ptr    = (int*)take((size_t)(NSEG + 1) * 4);
    int* sums       = (int*)take(512 * 4);
    int* sorted_src = (int*)take((size_t)N_EDGES * 4);
    ushort* BTp[4];
    for (int l = 0; l < 4; ++l) BTp[l] = (ushort*)take((size_t)OS[l] * 9 * KS[l] * 2);
    ushort* hbA = (ushort*)take((size_t)N_PAD * 256 * 2);   // ping
    ushort* hbB = (ushort*)take((size_t)N_PAD * 256 * 2);   // pong

    // ---- edge preprocessing (once per call) ----
    hipMemsetAsync(cnt, 0, (size_t)NSEG * 4, stream);
    count_edges<<<(N_EDGES + 255) / 256, 256, 0, stream>>>(dst, et, cnt);
    scan_pass1<<<SCAN_NB, 256, 0, stream>>>(cnt, sums);
    scan_pass2<<<1, 512, 0, stream>>>(sums, SCAN_NB);
    scan_pass3<<<SCAN_NB, 256, 0, stream>>>(cnt, sums, row_ptr);
    place_edges<<<(N_EDGES + 255) / 256, 256, 0, stream>>>(src, dst, et, row_ptr, cnt, sorted_src);

    // ---- weight pack ----
    for (int l = 0; l < 4; ++l) {
        int n = OS[l] * 9 * KS[l];
        convert_weights<<<(n + 255) / 256, 256, 0, stream>>>(W[l], RT[l], BTp[l], KS[l], OS[l]);
    }

    // ---- input to bf16 ----
    f32_to_bf16<<<(N_NODES * 128 / 4 + 255) / 256, 256, 0, stream>>>(x, hbA, N_NODES * 128 / 4);

    // ---- 4 fused layers ----
    const int GRID = N_PAD / 64;   // 782
    fused_layer<128, 256, false><<<GRID, 256, 0, stream>>>(hbA, BTp[0], BI[0], row_ptr, sorted_src, hbB, nullptr);
    fused_layer<256, 256, false><<<GRID, 256, 0, stream>>>(hbB, BTp[1], BI[1], row_ptr, sorted_src, hbA, nullptr);
    fused_layer<256, 256, false><<<GRID, 256, 0, stream>>>(hbA, BTp[2], BI[2], row_ptr, sorted_src, hbB, nullptr);
    fused_layer<256, 64,  true ><<<GRID, 256, 0, stream>>>(hbB, BTp[3], BI[3], row_ptr, sorted_src, nullptr, (float*)d_out);
}

// Round 6
// 837.942 us; speedup vs baseline: 1.5721x; 1.5721x over previous
//
#include <hip/hip_runtime.h>

#define N_NODES 50000
#define N_PAD   50048          // 391 * 128
#define N_EDGES 800000
#define N_REL   8
#define NSEG    (N_REL * N_NODES)      // 400000
#define SCAN_NB 391                    // ceil(NSEG / 1024)

typedef short bf16x8 __attribute__((ext_vector_type(8)));
typedef float f32x4  __attribute__((ext_vector_type(4)));

__device__ __forceinline__ ushort f2bf(float f) {
    union { float f; unsigned u; } c; c.f = f;
    unsigned u = c.u + 0x7fffu + ((c.u >> 16) & 1u);   // RNE
    return (ushort)(u >> 16);
}
__device__ __forceinline__ void add8(float* s, uint4 v) {
    unsigned u[4] = {v.x, v.y, v.z, v.w};
    #pragma unroll
    for (int k = 0; k < 4; ++k) {
        s[2 * k]     += __uint_as_float(u[k] << 16);
        s[2 * k + 1] += __uint_as_float(u[k] & 0xffff0000u);
    }
}
__device__ __forceinline__ void async16(const ushort* g, ushort* l) {
    __builtin_amdgcn_global_load_lds((const __attribute__((address_space(1))) void*)g,
                                     (__attribute__((address_space(3))) void*)l, 16, 0, 0);
}

// ---------------- edge preprocessing: counting sort by (rel*N + dst) ----------------

__global__ void count_edges(const int* __restrict__ dst, const int* __restrict__ et,
                            int* __restrict__ cnt) {
    int e = blockIdx.x * 256 + threadIdx.x;
    if (e < N_EDGES) atomicAdd(&cnt[et[e] * N_NODES + dst[e]], 1);
}

__global__ __launch_bounds__(256) void scan_pass1(const int* __restrict__ cnt,
                                                  int* __restrict__ sums) {
    __shared__ int sc[256];
    int b = blockIdx.x, t = threadIdx.x;
    int base = b * 1024 + t * 4;
    int v = 0;
    #pragma unroll
    for (int i = 0; i < 4; ++i) { int idx = base + i; if (idx < NSEG) v += cnt[idx]; }
    sc[t] = v; __syncthreads();
    for (int off = 1; off < 256; off <<= 1) {
        int x = (t >= off) ? sc[t - off] : 0;
        __syncthreads(); sc[t] += x; __syncthreads();
    }
    if (t == 255) sums[b] = sc[255];
}

__global__ __launch_bounds__(512) void scan_pass2(int* __restrict__ sums, int nb) {
    __shared__ int sc[512];
    int t = threadIdx.x;
    int v = (t < nb) ? sums[t] : 0;
    sc[t] = v; __syncthreads();
    for (int off = 1; off < 512; off <<= 1) {
        int x = (t >= off) ? sc[t - off] : 0;
        __syncthreads(); sc[t] += x; __syncthreads();
    }
    if (t < nb) sums[t] = sc[t] - v;     // exclusive
}

__global__ __launch_bounds__(256) void scan_pass3(const int* __restrict__ cnt,
                                                  const int* __restrict__ sums,
                                                  int* __restrict__ row_ptr) {
    __shared__ int sc[256];
    int b = blockIdx.x, t = threadIdx.x;
    int base = b * 1024 + t * 4;
    int e[4]; int v = 0;
    #pragma unroll
    for (int i = 0; i < 4; ++i) { int idx = base + i; e[i] = (idx < NSEG) ? cnt[idx] : 0; v += e[i]; }
    sc[t] = v; __syncthreads();
    for (int off = 1; off < 256; off <<= 1) {
        int x = (t >= off) ? sc[t - off] : 0;
        __syncthreads(); sc[t] += x; __syncthreads();
    }
    int run = sums[b] + (sc[t] - v);
    #pragma unroll
    for (int i = 0; i < 4; ++i) {
        int idx = base + i;
        if (idx < NSEG) row_ptr[idx] = run;
        run += e[i];
    }
    if (b == 0 && t == 0) row_ptr[NSEG] = N_EDGES;
}

// cnt doubles as the placement cursor (atomicSub); cnt is dead afterwards.
__global__ void place_edges(const int* __restrict__ src, const int* __restrict__ dst,
                            const int* __restrict__ et, const int* __restrict__ row_ptr,
                            int* __restrict__ cnt, int* __restrict__ sorted_src) {
    int e = blockIdx.x * 256 + threadIdx.x;
    if (e >= N_EDGES) return;
    int key = et[e] * N_NODES + dst[e];
    int old = atomicSub(&cnt[key], 1);
    sorted_src[row_ptr[key] + old - 1] = src[e];
}

// ---------------- weight pack: BT[col][k] bf16, col = r*O+o (r=8 -> root), zero-pad cols ----------------

__global__ void convert_weights(const float* __restrict__ W, const float* __restrict__ root,
                                ushort* __restrict__ BT, int K, int O, int NPAD) {
    int idx = blockIdx.x * 256 + threadIdx.x;
    if (idx >= NPAD * K) return;
    int col = idx / K, i = idx % K;
    float v = 0.0f;
    if (col < N_REL * O) {
        int r = col / O, o = col % O;
        v = W[((size_t)r * K + i) * O + o];
    } else if (col < (N_REL + 1) * O) {
        v = root[(size_t)i * O + (col - N_REL * O)];
    }
    BT[idx] = f2bf(v);
}

__global__ void f32_to_bf16(const float* __restrict__ in, ushort* __restrict__ out, int n4) {
    int i = blockIdx.x * 256 + threadIdx.x;
    if (i >= n4) return;
    float4 v = ((const float4*)in)[i];
    ushort4 s; s.x = f2bf(v.x); s.y = f2bf(v.y); s.z = f2bf(v.z); s.w = f2bf(v.w);
    ((ushort4*)out)[i] = s;
}

// ---------------- bf16 MFMA GEMM (m97): 128x128 tile, BK=32, global_load_lds staging ----------------
// Epilogue: per-wave 64x64 transpose through LDS -> full-line coalesced 16B stores
// (kills the ~230 MB write-allocate RFO fetch seen in round 3).
template<int K>
__global__ __launch_bounds__(256)
void gemm_mfma(const ushort* __restrict__ A, const ushort* __restrict__ BT,
               ushort* __restrict__ Y, int NW) {
    __shared__ ushort SMEM[4 * 64 * 72];        // 36864 B; k-loop: As|Bs (16 KB), epilogue: Ts
    ushort* As = SMEM;                          // 128*32 = 4096 ushorts
    ushort* Bs = SMEM + 4096;
    const int t = threadIdx.x;
    const int lane = t & 63;
    const int w = t >> 6;
    const int l16 = lane & 15, q = lane >> 4;
    const int wm = (w & 1) * 64, wn = (w >> 1) * 64;
    const int row0 = blockIdx.x * 128;
    const int col0 = blockIdx.y * 128;

    // staging: chunk c (0..511) = 16B; row = c>>2, kcol = (c&3)*8. Wave w handles
    // chunks [w*64, w*64+64) and [(w+4)*64, ...): LDS dst = wave-uniform base + lane*16.
    const int c0i = w * 64 + lane;
    const int c1i = c0i + 256;
    const size_t ga0 = (size_t)(c0i >> 2) * K + (size_t)(c0i & 3) * 8;
    const size_t ga1 = (size_t)(c1i >> 2) * K + (size_t)(c1i & 3) * 8;
    const ushort* Ab = A + (size_t)row0 * K;
    const ushort* Bb = BT + (size_t)col0 * K;
    ushort* lA0 = &As[w * 512];
    ushort* lA1 = &As[(w + 4) * 512];
    ushort* lB0 = &Bs[w * 512];
    ushort* lB1 = &Bs[(w + 4) * 512];

    f32x4 acc[4][4] = {};

    #pragma unroll
    for (int k0 = 0; k0 < K; k0 += 32) {
        __syncthreads();                       // previous iter's LDS reads done
        async16(Ab + k0 + ga0, lA0);
        async16(Ab + k0 + ga1, lA1);
        async16(Bb + k0 + ga0, lB0);
        async16(Bb + k0 + ga1, lB1);
        __syncthreads();                       // drains global_load_lds (vmcnt 0)
        bf16x8 a[4], b[4];
        #pragma unroll
        for (int i = 0; i < 4; ++i) {
            a[i] = *(const bf16x8*)&As[(wm + i * 16 + l16) * 32 + q * 8];
            b[i] = *(const bf16x8*)&Bs[(wn + i * 16 + l16) * 32 + q * 8];
        }
        #pragma unroll
        for (int i = 0; i < 4; ++i)
            #pragma unroll
            for (int j = 0; j < 4; ++j)
                acc[i][j] = __builtin_amdgcn_mfma_f32_16x16x32_bf16(a[i], b[j], acc[i][j], 0, 0, 0);
    }

    // ---- epilogue: transpose wave's 64x64 fragment via LDS (stride 72), then
    // full-line stores: lanes (L>>3 = row-in-group, L&7 = 16B chunk) cover
    // 8 rows x 128 B contiguous per instruction -> L2 sees whole-line writes.
    __syncthreads();                           // k-loop LDS reads done; reuse SMEM as Ts
    ushort* Ts = &SMEM[w * 64 * 72];
    // scatter phase: D mapping col=l16, row=q*4+reg (verified gfx950 layout)
    #pragma unroll
    for (int i = 0; i < 4; ++i)
        #pragma unroll
        for (int j = 0; j < 4; ++j)
            #pragma unroll
            for (int r = 0; r < 4; ++r)
                Ts[(i * 16 + q * 4 + r) * 72 + j * 16 + l16] = f2bf(acc[i][j][r]);
    // gather+store phase (wave-private region; compiler inserts lgkmcnt waits)
    const int rr = lane >> 3;                  // 0..7 row within group
    const int cc = (lane & 7) * 8;             // 16B chunk
    #pragma unroll
    for (int p = 0; p < 8; ++p) {
        int row = p * 8 + rr;                  // 0..63 local
        uint4 v = *(const uint4*)&Ts[row * 72 + cc];
        *(uint4*)(Y + (size_t)(row0 + wm + row) * NW + col0 + wn + cc) = v;
    }
}

// ---------------- fused gather: out[d] = act( root + bias + sum_r mean_r ) ----------------
// Thread owns (dst node, 8-col chunk); loops relations; no atomics.
template<int O>
__global__ __launch_bounds__(256)
void gather_kernel(const ushort* __restrict__ Y, int NW,
                   const int* __restrict__ row_ptr, const int* __restrict__ sorted_src,
                   const float* __restrict__ bias,
                   float* __restrict__ out_f32, ushort* __restrict__ out_bf16, int relu) {
    constexpr int TPN = O / 8;
    int d = blockIdx.x * (256 / TPN) + threadIdx.x / TPN;
    if (d >= N_NODES) return;
    int c0 = (threadIdx.x % TPN) * 8;
    float sum[8] = {};
    add8(sum, *(const uint4*)(Y + (size_t)d * NW + N_REL * O + c0));   // root slice
    #pragma unroll
    for (int k = 0; k < 8; ++k) sum[k] += bias[c0 + k];
    for (int r = 0; r < N_REL; ++r) {
        int base = r * N_NODES + d;
        int s0 = row_ptr[base], s1 = row_ptr[base + 1];
        if (s1 <= s0) continue;
        float ps[8] = {};
        const ushort* Yc = Y + r * O + c0;
        for (int e = s0; e < s1; ++e)
            add8(ps, *(const uint4*)(Yc + (size_t)sorted_src[e] * NW));
        float inv = 1.0f / (float)(s1 - s0);
        #pragma unroll
        for (int k = 0; k < 8; ++k) sum[k] += ps[k] * inv;
    }
    if (relu) {
        #pragma unroll
        for (int k = 0; k < 8; ++k) sum[k] = fmaxf(sum[k], 0.0f);
    }
    if (out_bf16) {
        ushort o[8];
        #pragma unroll
        for (int k = 0; k < 8; ++k) o[k] = f2bf(sum[k]);
        *(uint4*)(out_bf16 + (size_t)d * O + c0) = *(const uint4*)o;
    } else {
        float* p = out_f32 + (size_t)d * O + c0;
        *(float4*)p = make_float4(sum[0], sum[1], sum[2], sum[3]);
        *(float4*)(p + 4) = make_float4(sum[4], sum[5], sum[6], sum[7]);
    }
}

// ---------------- host side ----------------

extern "C" void kernel_launch(void* const* d_in, const int* in_sizes, int n_in,
                              void* d_out, int out_size, void* d_ws, size_t ws_size,
                              hipStream_t stream) {
    const float* x  = (const float*)d_in[0];
    const int*   ei = (const int*)d_in[1];
    const int*   et = (const int*)d_in[2];
    const float* W[4]  = {(const float*)d_in[3], (const float*)d_in[6], (const float*)d_in[9],  (const float*)d_in[12]};
    const float* RT[4] = {(const float*)d_in[4], (const float*)d_in[7], (const float*)d_in[10], (const float*)d_in[13]};
    const float* BI[4] = {(const float*)d_in[5], (const float*)d_in[8], (const float*)d_in[11], (const float*)d_in[14]};
    const int KS[4] = {128, 256, 256, 256};
    const int OS[4] = {256, 256, 256, 64};
    const int NP[4] = {2304, 2304, 2304, 640};   // packed+padded BT rows (= Y width)
    const int* src = ei;
    const int* dst = ei + N_EDGES;

    // ---- workspace carve-up (identical footprint to round-3 plan A: proven to fit) ----
    char* ws = (char*)d_ws;
    size_t off = 0;
    auto take = [&](size_t bytes) -> char* {
        char* p = ws + off;
        off = (off + bytes + 255) & ~(size_t)255;
        return p;
    };
    int* cnt        = (int*)take((size_t)NSEG * 4);
    int* row_ptr    = (int*)take((size_t)(NSEG + 1) * 4);
    int* sums       = (int*)take(512 * 4);
    int* sorted_src = (int*)take((size_t)N_EDGES * 4);
    ushort* BTp[4];
    for (int l = 0; l < 4; ++l) BTp[l] = (ushort*)take((size_t)NP[l] * KS[l] * 2);
    ushort* hb = (ushort*)take((size_t)N_PAD * 256 * 2);
    ushort* Yb = (ushort*)take((size_t)N_PAD * 2304 * 2);

    // ---- edge preprocessing (once per call) ----
    hipMemsetAsync(cnt, 0, (size_t)NSEG * 4, stream);
    count_edges<<<(N_EDGES + 255) / 256, 256, 0, stream>>>(dst, et, cnt);
    scan_pass1<<<SCAN_NB, 256, 0, stream>>>(cnt, sums);
    scan_pass2<<<1, 512, 0, stream>>>(sums, SCAN_NB);
    scan_pass3<<<SCAN_NB, 256, 0, stream>>>(cnt, sums, row_ptr);
    place_edges<<<(N_EDGES + 255) / 256, 256, 0, stream>>>(src, dst, et, row_ptr, cnt, sorted_src);

    // ---- weight pack ----
    for (int l = 0; l < 4; ++l) {
        int n = NP[l] * KS[l];
        convert_weights<<<(n + 255) / 256, 256, 0, stream>>>(W[l], RT[l], BTp[l], KS[l], OS[l], NP[l]);
    }

    // ---- input to bf16 ----
    f32_to_bf16<<<(N_NODES * 128 / 4 + 255) / 256, 256, 0, stream>>>(x, hb, N_NODES * 128 / 4);

    // ---- 4 layers: one wide GEMM + one fused gather each ----
    for (int l = 0; l < 4; ++l) {
        const int K = KS[l], O = OS[l];
        const bool last = (l == 3);
        dim3 g(N_PAD / 128, NP[l] / 128), b(256);
        if (K == 128) gemm_mfma<128><<<g, b, 0, stream>>>(hb, BTp[l], Yb, NP[l]);
        else          gemm_mfma<256><<<g, b, 0, stream>>>(hb, BTp[l], Yb, NP[l]);
        if (O == 256)
            gather_kernel<256><<<dim3((N_NODES + 7) / 8), 256, 0, stream>>>(
                Yb, NP[l], row_ptr, sorted_src, BI[l], nullptr, hb, 1);
        else
            gather_kernel<64><<<dim3((N_NODES + 31) / 32), 256, 0, stream>>>(
                Yb, NP[l], row_ptr, sorted_src, BI[l], (float*)d_out, nullptr, 0);
    }
}

// Round 7
// 765.812 us; speedup vs baseline: 1.7202x; 1.0942x over previous
//
#include <hip/hip_runtime.h>

#define N_NODES 50000
#define N_PAD   50048          // 391 * 128
#define N_EDGES 800000
#define N_REL   8
#define NSEG    (N_REL * N_NODES)      // 400000
#define SCAN_NB 391                    // ceil(NSEG / 1024)

typedef short bf16x8 __attribute__((ext_vector_type(8)));
typedef float f32x4  __attribute__((ext_vector_type(4)));

__device__ __forceinline__ ushort f2bf(float f) {
    union { float f; unsigned u; } c; c.f = f;
    unsigned u = c.u + 0x7fffu + ((c.u >> 16) & 1u);   // RNE
    return (ushort)(u >> 16);
}
__device__ __forceinline__ void add8(float* s, uint4 v) {
    unsigned u[4] = {v.x, v.y, v.z, v.w};
    #pragma unroll
    for (int k = 0; k < 4; ++k) {
        s[2 * k]     += __uint_as_float(u[k] << 16);
        s[2 * k + 1] += __uint_as_float(u[k] & 0xffff0000u);
    }
}
__device__ __forceinline__ void async16(const ushort* g, ushort* l) {
    __builtin_amdgcn_global_load_lds((const __attribute__((address_space(1))) void*)g,
                                     (__attribute__((address_space(3))) void*)l, 16, 0, 0);
}

// ---------------- edge preprocessing: counting sort by (rel*N + dst) ----------------

__global__ void count_edges(const int* __restrict__ dst, const int* __restrict__ et,
                            int* __restrict__ cnt) {
    int e = blockIdx.x * 256 + threadIdx.x;
    if (e < N_EDGES) atomicAdd(&cnt[et[e] * N_NODES + dst[e]], 1);
}

__global__ __launch_bounds__(256) void scan_pass1(const int* __restrict__ cnt,
                                                  int* __restrict__ sums) {
    __shared__ int sc[256];
    int b = blockIdx.x, t = threadIdx.x;
    int base = b * 1024 + t * 4;
    int v = 0;
    #pragma unroll
    for (int i = 0; i < 4; ++i) { int idx = base + i; if (idx < NSEG) v += cnt[idx]; }
    sc[t] = v; __syncthreads();
    for (int off = 1; off < 256; off <<= 1) {
        int x = (t >= off) ? sc[t - off] : 0;
        __syncthreads(); sc[t] += x; __syncthreads();
    }
    if (t == 255) sums[b] = sc[255];
}

__global__ __launch_bounds__(512) void scan_pass2(int* __restrict__ sums, int nb) {
    __shared__ int sc[512];
    int t = threadIdx.x;
    int v = (t < nb) ? sums[t] : 0;
    sc[t] = v; __syncthreads();
    for (int off = 1; off < 512; off <<= 1) {
        int x = (t >= off) ? sc[t - off] : 0;
        __syncthreads(); sc[t] += x; __syncthreads();
    }
    if (t < nb) sums[t] = sc[t] - v;     // exclusive
}

__global__ __launch_bounds__(256) void scan_pass3(const int* __restrict__ cnt,
                                                  const int* __restrict__ sums,
                                                  int* __restrict__ row_ptr) {
    __shared__ int sc[256];
    int b = blockIdx.x, t = threadIdx.x;
    int base = b * 1024 + t * 4;
    int e[4]; int v = 0;
    #pragma unroll
    for (int i = 0; i < 4; ++i) { int idx = base + i; e[i] = (idx < NSEG) ? cnt[idx] : 0; v += e[i]; }
    sc[t] = v; __syncthreads();
    for (int off = 1; off < 256; off <<= 1) {
        int x = (t >= off) ? sc[t - off] : 0;
        __syncthreads(); sc[t] += x; __syncthreads();
    }
    int run = sums[b] + (sc[t] - v);
    #pragma unroll
    for (int i = 0; i < 4; ++i) {
        int idx = base + i;
        if (idx < NSEG) row_ptr[idx] = run;
        run += e[i];
    }
    if (b == 0 && t == 0) row_ptr[NSEG] = N_EDGES;
}

// cnt doubles as the placement cursor (atomicSub); cnt is dead afterwards.
__global__ void place_edges(const int* __restrict__ src, const int* __restrict__ dst,
                            const int* __restrict__ et, const int* __restrict__ row_ptr,
                            int* __restrict__ cnt, int* __restrict__ sorted_src) {
    int e = blockIdx.x * 256 + threadIdx.x;
    if (e >= N_EDGES) return;
    int key = et[e] * N_NODES + dst[e];
    int old = atomicSub(&cnt[key], 1);
    sorted_src[row_ptr[key] + old - 1] = src[e];
}

// ---------------- weight pack: BT[col][k] bf16, col = r*O+o (r=8 -> root), zero-pad cols ----------------

__global__ void convert_weights(const float* __restrict__ W, const float* __restrict__ root,
                                ushort* __restrict__ BT, int K, int O, int NPAD) {
    int idx = blockIdx.x * 256 + threadIdx.x;
    if (idx >= NPAD * K) return;
    int col = idx / K, i = idx % K;
    float v = 0.0f;
    if (col < N_REL * O) {
        int r = col / O, o = col % O;
        v = W[((size_t)r * K + i) * O + o];
    } else if (col < (N_REL + 1) * O) {
        v = root[(size_t)i * O + (col - N_REL * O)];
    }
    BT[idx] = f2bf(v);
}

__global__ void f32_to_bf16(const float* __restrict__ in, ushort* __restrict__ out, int n4) {
    int i = blockIdx.x * 256 + threadIdx.x;
    if (i >= n4) return;
    float4 v = ((const float4*)in)[i];
    ushort4 s; s.x = f2bf(v.x); s.y = f2bf(v.y); s.z = f2bf(v.z); s.w = f2bf(v.w);
    ((ushort4*)out)[i] = s;
}

// ---------------- bf16 MFMA GEMM (m97): 128x128 tile, BK=32, global_load_lds staging ----------------
// Grid: blockIdx.x = COLUMN block (fast), blockIdx.y = row block -> all col-blocks of a
// 128-row stripe run near-simultaneously and share the stripe's A-tile via L2/L3
// (round-6 counter evidence: row-fast order re-swept A 18x = 232 MB HBM fetch).
// Epilogue: two-pass 32-row transpose through wave-private LDS -> full-line 128B stores.
template<int K>
__global__ __launch_bounds__(256)
void gemm_mfma(const ushort* __restrict__ A, const ushort* __restrict__ BT,
               ushort* __restrict__ Y, int NW) {
    __shared__ ushort SMEM[9216];               // 18432 B: k-loop As|Bs (16 KB) / epilogue Ts
    ushort* As = SMEM;                          // 128*32 = 4096 ushorts
    ushort* Bs = SMEM + 4096;
    const int t = threadIdx.x;
    const int lane = t & 63;
    const int w = t >> 6;
    const int l16 = lane & 15, q = lane >> 4;
    const int wm = (w & 1) * 64, wn = (w >> 1) * 64;
    const int col0 = blockIdx.x * 128;          // x = col block (fast-varying)
    const int row0 = blockIdx.y * 128;

    // staging: chunk c (0..511) = 16B; row = c>>2, kcol = (c&3)*8. Wave w handles
    // chunks [w*64, w*64+64) and [(w+4)*64, ...): LDS dst = wave-uniform base + lane*16.
    const int c0i = w * 64 + lane;
    const int c1i = c0i + 256;
    const size_t ga0 = (size_t)(c0i >> 2) * K + (size_t)(c0i & 3) * 8;
    const size_t ga1 = (size_t)(c1i >> 2) * K + (size_t)(c1i & 3) * 8;
    const ushort* Ab = A + (size_t)row0 * K;
    const ushort* Bb = BT + (size_t)col0 * K;
    ushort* lA0 = &As[w * 512];
    ushort* lA1 = &As[(w + 4) * 512];
    ushort* lB0 = &Bs[w * 512];
    ushort* lB1 = &Bs[(w + 4) * 512];

    f32x4 acc[4][4] = {};

    #pragma unroll
    for (int k0 = 0; k0 < K; k0 += 32) {
        __syncthreads();                       // previous iter's LDS reads done
        async16(Ab + k0 + ga0, lA0);
        async16(Ab + k0 + ga1, lA1);
        async16(Bb + k0 + ga0, lB0);
        async16(Bb + k0 + ga1, lB1);
        __syncthreads();                       // drains global_load_lds (vmcnt 0)
        bf16x8 a[4], b[4];
        #pragma unroll
        for (int i = 0; i < 4; ++i) {
            a[i] = *(const bf16x8*)&As[(wm + i * 16 + l16) * 32 + q * 8];
            b[i] = *(const bf16x8*)&Bs[(wn + i * 16 + l16) * 32 + q * 8];
        }
        #pragma unroll
        for (int i = 0; i < 4; ++i)
            #pragma unroll
            for (int j = 0; j < 4; ++j)
                acc[i][j] = __builtin_amdgcn_mfma_f32_16x16x32_bf16(a[i], b[j], acc[i][j], 0, 0, 0);
    }

    // ---- epilogue: two-pass transpose via wave-private LDS (32 rows x stride 72),
    // then full-line stores: 8 lanes cover 128 B of one row per instruction.
    __syncthreads();                           // k-loop LDS reads done; reuse SMEM as Ts
    ushort* Ts = &SMEM[w * 32 * 72];
    const int rr = lane >> 3;                  // 0..7 row within 8-row group
    const int cc = (lane & 7) * 8;             // 16B chunk within row
    #pragma unroll
    for (int half = 0; half < 2; ++half) {
        // scatter: D mapping col=l16, row=q*4+reg (verified gfx950 layout)
        #pragma unroll
        for (int i = 0; i < 2; ++i)
            #pragma unroll
            for (int j = 0; j < 4; ++j)
                #pragma unroll
                for (int r = 0; r < 4; ++r)
                    Ts[(i * 16 + q * 4 + r) * 72 + j * 16 + l16] = f2bf(acc[half * 2 + i][j][r]);
        // gather+store (wave-private region; compiler orders LDS ops via lgkmcnt)
        #pragma unroll
        for (int p = 0; p < 4; ++p) {
            int row = p * 8 + rr;              // 0..31 local
            uint4 v = *(const uint4*)&Ts[row * 72 + cc];
            *(uint4*)(Y + (size_t)(row0 + wm + half * 32 + row) * NW + col0 + wn + cc) = v;
        }
    }
}

// ---------------- fused gather: out[d] = act( root + bias + sum_r mean_r ) ----------------
// Thread owns (dst node, 8-col chunk); loops relations; no atomics.
template<int O>
__global__ __launch_bounds__(256)
void gather_kernel(const ushort* __restrict__ Y, int NW,
                   const int* __restrict__ row_ptr, const int* __restrict__ sorted_src,
                   const float* __restrict__ bias,
                   float* __restrict__ out_f32, ushort* __restrict__ out_bf16, int relu) {
    constexpr int TPN = O / 8;
    int d = blockIdx.x * (256 / TPN) + threadIdx.x / TPN;
    if (d >= N_NODES) return;
    int c0 = (threadIdx.x % TPN) * 8;
    float sum[8] = {};
    add8(sum, *(const uint4*)(Y + (size_t)d * NW + N_REL * O + c0));   // root slice
    #pragma unroll
    for (int k = 0; k < 8; ++k) sum[k] += bias[c0 + k];
    for (int r = 0; r < N_REL; ++r) {
        int base = r * N_NODES + d;
        int s0 = row_ptr[base], s1 = row_ptr[base + 1];
        if (s1 <= s0) continue;
        float ps[8] = {};
        const ushort* Yc = Y + r * O + c0;
        for (int e = s0; e < s1; ++e)
            add8(ps, *(const uint4*)(Yc + (size_t)sorted_src[e] * NW));
        float inv = 1.0f / (float)(s1 - s0);
        #pragma unroll
        for (int k = 0; k < 8; ++k) sum[k] += ps[k] * inv;
    }
    if (relu) {
        #pragma unroll
        for (int k = 0; k < 8; ++k) sum[k] = fmaxf(sum[k], 0.0f);
    }
    if (out_bf16) {
        ushort o[8];
        #pragma unroll
        for (int k = 0; k < 8; ++k) o[k] = f2bf(sum[k]);
        *(uint4*)(out_bf16 + (size_t)d * O + c0) = *(const uint4*)o;
    } else {
        float* p = out_f32 + (size_t)d * O + c0;
        *(float4*)p = make_float4(sum[0], sum[1], sum[2], sum[3]);
        *(float4*)(p + 4) = make_float4(sum[4], sum[5], sum[6], sum[7]);
    }
}

// ---------------- host side ----------------

extern "C" void kernel_launch(void* const* d_in, const int* in_sizes, int n_in,
                              void* d_out, int out_size, void* d_ws, size_t ws_size,
                              hipStream_t stream) {
    const float* x  = (const float*)d_in[0];
    const int*   ei = (const int*)d_in[1];
    const int*   et = (const int*)d_in[2];
    const float* W[4]  = {(const float*)d_in[3], (const float*)d_in[6], (const float*)d_in[9],  (const float*)d_in[12]};
    const float* RT[4] = {(const float*)d_in[4], (const float*)d_in[7], (const float*)d_in[10], (const float*)d_in[13]};
    const float* BI[4] = {(const float*)d_in[5], (const float*)d_in[8], (const float*)d_in[11], (const float*)d_in[14]};
    const int KS[4] = {128, 256, 256, 256};
    const int OS[4] = {256, 256, 256, 64};
    const int NP[4] = {2304, 2304, 2304, 640};   // packed+padded BT rows (= Y width)
    const int* src = ei;
    const int* dst = ei + N_EDGES;

    // ---- workspace carve-up (identical footprint to round-3 plan A: proven to fit) ----
    char* ws = (char*)d_ws;
    size_t off = 0;
    auto take = [&](size_t bytes) -> char* {
        char* p = ws + off;
        off = (off + bytes + 255) & ~(size_t)255;
        return p;
    };
    int* cnt        = (int*)take((size_t)NSEG * 4);
    int* row_ptr    = (int*)take((size_t)(NSEG + 1) * 4);
    int* sums       = (int*)take(512 * 4);
    int* sorted_src = (int*)take((size_t)N_EDGES * 4);
    ushort* BTp[4];
    for (int l = 0; l < 4; ++l) BTp[l] = (ushort*)take((size_t)NP[l] * KS[l] * 2);
    ushort* hb = (ushort*)take((size_t)N_PAD * 256 * 2);
    ushort* Yb = (ushort*)take((size_t)N_PAD * 2304 * 2);

    // ---- edge preprocessing (once per call) ----
    hipMemsetAsync(cnt, 0, (size_t)NSEG * 4, stream);
    count_edges<<<(N_EDGES + 255) / 256, 256, 0, stream>>>(dst, et, cnt);
    scan_pass1<<<SCAN_NB, 256, 0, stream>>>(cnt, sums);
    scan_pass2<<<1, 512, 0, stream>>>(sums, SCAN_NB);
    scan_pass3<<<SCAN_NB, 256, 0, stream>>>(cnt, sums, row_ptr);
    place_edges<<<(N_EDGES + 255) / 256, 256, 0, stream>>>(src, dst, et, row_ptr, cnt, sorted_src);

    // ---- weight pack ----
    for (int l = 0; l < 4; ++l) {
        int n = NP[l] * KS[l];
        convert_weights<<<(n + 255) / 256, 256, 0, stream>>>(W[l], RT[l], BTp[l], KS[l], OS[l], NP[l]);
    }

    // ---- input to bf16 ----
    f32_to_bf16<<<(N_NODES * 128 / 4 + 255) / 256, 256, 0, stream>>>(x, hb, N_NODES * 128 / 4);

    // ---- 4 layers: one wide GEMM + one fused gather each ----
    for (int l = 0; l < 4; ++l) {
        const int K = KS[l], O = OS[l];
        dim3 g(NP[l] / 128, N_PAD / 128), b(256);   // x = col block (fast) for A-reuse
        if (K == 128) gemm_mfma<128><<<g, b, 0, stream>>>(hb, BTp[l], Yb, NP[l]);
        else          gemm_mfma<256><<<g, b, 0, stream>>>(hb, BTp[l], Yb, NP[l]);
        if (O == 256)
            gather_kernel<256><<<dim3((N_NODES + 7) / 8), 256, 0, stream>>>(
                Yb, NP[l], row_ptr, sorted_src, BI[l], nullptr, hb, 1);
        else
            gather_kernel<64><<<dim3((N_NODES + 31) / 32), 256, 0, stream>>>(
                Yb, NP[l], row_ptr, sorted_src, BI[l], (float*)d_out, nullptr, 0);
    }
}